// Round 5
// baseline (9495.280 us; speedup 1.0000x reference)
//
#include <hip/hip_runtime.h>
#include <math.h>

#define BB 256   // batch
#define TT 128   // time steps
#define DD 256   // input dim
#define UU 512   // units
#define G5 (5 * UU)   // 2560
#define G4 (4 * UU)   // 2048 (packed width for rk and tk)
#define NBLK 256
#define GBLK 32       // blocks per barrier group (same bm)

__device__ __forceinline__ float hsig(float x) {
    return fminf(fmaxf(0.2f * x + 0.5f, 0.0f), 1.0f);
}

// Cross-block data discipline: EVERY access to hT/h1aT/h1bT/prl/xg goes
// through SYSTEM-scope relaxed atomics (sc0+sc1: bypass vL1 AND the
// non-coherent per-XCD L2, serve/land at the memory-side LLC). Round-4
// post-mortem: agent scope (sc1 only) still allowed vL1 hits -> rare
// one-phase-stale reads (absmax 0.0215 vs 0.0039 floor). System-relaxed
// ops emit NO cache-maintenance instructions, so weights stay L2-resident
// across all 384 phases (round-2/3 lesson: wbl2/inv per barrier = 2-10x).
__device__ __forceinline__ void st_sys(float* p, float v) {
    __hip_atomic_store(p, v, __ATOMIC_RELAXED, __HIP_MEMORY_SCOPE_SYSTEM);
}
__device__ __forceinline__ float ld_sys(const float* p) {
    return __hip_atomic_load(p, __ATOMIC_RELAXED, __HIP_MEMORY_SCOPE_SYSTEM);
}

// ---------------------------------------------------------------------------
// Pack weights into gate-interleaved layout: col = u*4 + g   (verified layout)
// ---------------------------------------------------------------------------
__global__ __launch_bounds__(256) void pack_weights(
    const float* __restrict__ rk, const float* __restrict__ tk,
    float* __restrict__ rkp, float* __restrict__ tkp0, float* __restrict__ tkp1)
{
    int idx = blockIdx.x * 256 + threadIdx.x;   // 0 .. 512*2048
    int k = idx >> 11;
    int c = idx & 2047;
    int u = c >> 2;
    int g = c & 3;
    rkp[idx] = rk[k * G4 + g * UU + u];
    float t0 = 0.f, t1 = 0.f;
    if (g < 3) {
        t0 = tk[(size_t)k * (3 * UU) + g * UU + u];
        t1 = tk[(size_t)(UU + k) * (3 * UU) + g * UU + u];
    }
    tkp0[idx] = t0;
    tkp1[idx] = t1;
}

// h state kept transposed: hT[u][b]  (u-major) so GEMM A-staging is coalesced
__global__ __launch_bounds__(256) void init_hT(
    const float* __restrict__ h0, float* __restrict__ hT)
{
    int idx = blockIdx.x * 256 + threadIdx.x;   // 0 .. 131071
    int u = idx >> 8;
    int b = idx & 255;
    hT[idx] = h0[(size_t)b * UU + u];
}

// ---------------------------------------------------------------------------
// Group-local monotonic barrier (32 blocks sharing the same bm). Arrive =
// relaxed agent fetch_add(1); wait until count >= phase. Ordering argument:
// __syncthreads drains each wave's vmcnt (all st_sys stores completed = at
// LLC) before thread0's RMW; a waiter that observes count>=phase therefore
// observes all pre-barrier LLC data via ld_sys. NO cache-maintenance ops.
// sched_barrier(0) = compile-time fence against hoisting loads across.
// ---------------------------------------------------------------------------
__device__ __forceinline__ void gbar(unsigned* cnt, unsigned& phase) {
    __syncthreads();
    if (threadIdx.x == 0) {
        phase += GBLK;
        __hip_atomic_fetch_add(cnt, 1u, __ATOMIC_RELAXED, __HIP_MEMORY_SCOPE_AGENT);
        while ((int)(__hip_atomic_load(cnt, __ATOMIC_RELAXED, __HIP_MEMORY_SCOPE_AGENT) - phase) < 0)
            __builtin_amdgcn_s_sleep(2);
        __builtin_amdgcn_fence(__ATOMIC_ACQUIRE, "workgroup");   // waitcnt only
    }
    __syncthreads();
    __builtin_amdgcn_sched_barrier(0);
}

// ---------------------------------------------------------------------------
// Shared GEMM phase for recur/trans: C(256x2048,packed) = A_T^T @ Wp, K=512.
// bid -> bm=(bid>>5)*32 rows, bn=(bid&31)*64 packed cols. 4 waves k-split;
// per-lane 4x8 microtile; cross-wave sum via LDS; (wave,lane) owns row
// bm+r8*4+kg, cols bn+c8*8..+7. BK=64 tiles, register double-buffered.
// A (activations) = cross-block data -> system-scope scalar loads.
// W (weights) = plain loads -> L2-hit every step after the first.
// ---------------------------------------------------------------------------
__device__ __forceinline__ void rt_gemm(
    const float* __restrict__ AT,   // [512][256] k-major (transposed activ.)
    const float* __restrict__ Wp,   // [512][2048] packed
    int bm, int bn, int tid,
    float (* __restrict__ As)[36], float (* __restrict__ Ws)[80],
    float* __restrict__ RedF,
    float* __restrict__ s, int& row_out)
{
    const int lane = tid & 63;
    const int kg = tid >> 6;          // wave = k-split group
    const int r8 = lane & 7;
    const int c8 = lane >> 3;
    const int akr = tid >> 3;         // A staging: k-row 0..31 (+32)
    const int amc = (tid & 7) * 4;    //            m-col
    const int wwr = tid >> 4;         // W staging: k-row 0..15 (+16/32/48)
    const int wwc = (tid & 15) * 4;   //            n-col

    const float* ap = AT + (size_t)akr * BB + bm + amc;
    const float* wp = Wp + (size_t)wwr * G4 + bn + wwc;

    float a0[4], a1[4];
#pragma unroll
    for (int j = 0; j < 4; ++j) {
        a0[j] = ld_sys(ap + j);
        a1[j] = ld_sys(ap + 32 * BB + j);
    }
    float4 w0 = *(const float4*)wp;
    float4 w1 = *(const float4*)(wp + 16 * G4);
    float4 w2 = *(const float4*)(wp + 32 * G4);
    float4 w3 = *(const float4*)(wp + 48 * G4);

    float acc[4][8];
#pragma unroll
    for (int r = 0; r < 4; ++r)
#pragma unroll
        for (int j = 0; j < 8; ++j) acc[r][j] = 0.f;

#pragma unroll 1
    for (int tile = 0; tile < 8; ++tile) {
        __syncthreads();              // prev tile reads / prev phase LDS done
        As[akr][amc + 0] = a0[0]; As[akr][amc + 1] = a0[1];
        As[akr][amc + 2] = a0[2]; As[akr][amc + 3] = a0[3];
        As[akr + 32][amc + 0] = a1[0]; As[akr + 32][amc + 1] = a1[1];
        As[akr + 32][amc + 2] = a1[2]; As[akr + 32][amc + 3] = a1[3];
        *(float4*)&Ws[wwr][wwc] = w0;
        *(float4*)&Ws[wwr + 16][wwc] = w1;
        *(float4*)&Ws[wwr + 32][wwc] = w2;
        *(float4*)&Ws[wwr + 48][wwc] = w3;
        if (tile < 7) {               // prefetch next tile into regs
            ap += 64 * BB;
            wp += 64 * G4;
#pragma unroll
            for (int j = 0; j < 4; ++j) {
                a0[j] = ld_sys(ap + j);
                a1[j] = ld_sys(ap + 32 * BB + j);
            }
            w0 = *(const float4*)wp;
            w1 = *(const float4*)(wp + 16 * G4);
            w2 = *(const float4*)(wp + 32 * G4);
            w3 = *(const float4*)(wp + 48 * G4);
        }
        __syncthreads();              // staged tile visible
        const int kb = kg * 16;
#pragma unroll
        for (int q = 0; q < 16; ++q) {
            float4 av4 = *(const float4*)&As[kb + q][r8 * 4];
            float4 wv0 = *(const float4*)&Ws[kb + q][c8 * 8];
            float4 wv1 = *(const float4*)&Ws[kb + q][c8 * 8 + 4];
            float av[4] = {av4.x, av4.y, av4.z, av4.w};
            float wv[8] = {wv0.x, wv0.y, wv0.z, wv0.w, wv1.x, wv1.y, wv1.z, wv1.w};
#pragma unroll
            for (int r = 0; r < 4; ++r)
#pragma unroll
                for (int j = 0; j < 8; ++j)
                    acc[r][j] += av[r] * wv[j];
        }
    }

    // cross-wave k reduction (stride-64 lanes -> conflict-free)
#pragma unroll
    for (int r = 0; r < 4; ++r)
#pragma unroll
        for (int j = 0; j < 8; ++j)
            RedF[(kg * 32 + r * 8 + j) * 64 + lane] = acc[r][j];
    __syncthreads();
#pragma unroll
    for (int j = 0; j < 8; ++j)
        s[j] = RedF[(kg * 8 + j) * 64 + lane]
             + RedF[(32 + kg * 8 + j) * 64 + lane]
             + RedF[(64 + kg * 8 + j) * 64 + lane]
             + RedF[(96 + kg * 8 + j) * 64 + lane];
    row_out = bm + r8 * 4 + kg;
}

// ---------------------------------------------------------------------------
// xg phase: xg[t][m][n] = x[m][t][:] @ Wxg + bias0, M=256 K=256 N=2560.
// Ntile=80, per-lane 4x(8+2) microtile. x/Wxg are kernel inputs -> plain
// loads (L2-cached); output is cross-block -> st_sys.
// ---------------------------------------------------------------------------
__device__ __forceinline__ void xg_phase(
    const float* __restrict__ x, const float* __restrict__ Wxg,
    const float* __restrict__ bias0, float* __restrict__ xgdst, int t,
    int bm, int bnx, int tid,
    float (* __restrict__ As)[36], float (* __restrict__ Ws)[80],
    float* __restrict__ RedF)
{
    const int lane = tid & 63;
    const int kg = tid >> 6;
    const int r8 = lane & 7;
    const int c8 = lane >> 3;
    const int xbr = tid >> 3;            // 0..31 batch row
    const int xdc = (tid & 7) * 8;       // 0..56 d base

    float acc[4][10];
#pragma unroll
    for (int r = 0; r < 4; ++r)
#pragma unroll
        for (int c = 0; c < 10; ++c) acc[r][c] = 0.f;

    const float* xrow = x + ((size_t)(bm + xbr) * TT + t) * DD;

#pragma unroll 1
    for (int tile = 0; tile < 4; ++tile) {
        const int k0 = tile * 64;
        float4 xa0 = *(const float4*)(xrow + k0 + xdc);
        float4 xa1 = *(const float4*)(xrow + k0 + xdc + 4);
        float4 wv[5];
#pragma unroll
        for (int l = 0; l < 5; ++l) {
            int idx = tid + l * 256;         // 0..1279 covers 64x80 / 4
            int wrow = idx / 20;
            int wcol = (idx % 20) * 4;
            wv[l] = *(const float4*)(Wxg + (size_t)(k0 + wrow) * G5 + bnx + wcol);
        }
        __syncthreads();
        As[xdc + 0][xbr] = xa0.x; As[xdc + 1][xbr] = xa0.y;
        As[xdc + 2][xbr] = xa0.z; As[xdc + 3][xbr] = xa0.w;
        As[xdc + 4][xbr] = xa1.x; As[xdc + 5][xbr] = xa1.y;
        As[xdc + 6][xbr] = xa1.z; As[xdc + 7][xbr] = xa1.w;
#pragma unroll
        for (int l = 0; l < 5; ++l) {
            int idx = tid + l * 256;
            int wrow = idx / 20;
            int wcol = (idx % 20) * 4;
            *(float4*)&Ws[wrow][wcol] = wv[l];
        }
        __syncthreads();
        const int kb = kg * 16;
#pragma unroll
        for (int q = 0; q < 16; ++q) {
            float4 av4 = *(const float4*)&As[kb + q][r8 * 4];
            float4 wv0 = *(const float4*)&Ws[kb + q][c8 * 8];
            float4 wv1 = *(const float4*)&Ws[kb + q][c8 * 8 + 4];
            float2 wv2 = *(const float2*)&Ws[kb + q][64 + c8 * 2];
            float av[4] = {av4.x, av4.y, av4.z, av4.w};
            float wvv[10] = {wv0.x, wv0.y, wv0.z, wv0.w,
                             wv1.x, wv1.y, wv1.z, wv1.w, wv2.x, wv2.y};
#pragma unroll
            for (int r = 0; r < 4; ++r)
#pragma unroll
                for (int c = 0; c < 10; ++c)
                    acc[r][c] += av[r] * wvv[c];
        }
    }

#pragma unroll
    for (int r = 0; r < 4; ++r)
#pragma unroll
        for (int c = 0; c < 10; ++c)
            RedF[(kg * 40 + r * 10 + c) * 64 + lane] = acc[r][c];
    __syncthreads();
    const int row = bm + r8 * 4 + kg;
#pragma unroll
    for (int c = 0; c < 10; ++c) {
        float sv = RedF[(kg * 10 + c) * 64 + lane]
                 + RedF[(40 + kg * 10 + c) * 64 + lane]
                 + RedF[(80 + kg * 10 + c) * 64 + lane]
                 + RedF[(120 + kg * 10 + c) * 64 + lane];
        int n = bnx + (c < 8 ? c8 * 8 + c : 64 + c8 * 2 + (c - 8));
        st_sys(&xgdst[(size_t)row * G5 + n], sv + bias0[n]);
    }
}

// ---------------------------------------------------------------------------
// Persistent scan kernel: 256 blocks (1/CU) x 256 threads, plain launch.
// Per step: R -> gbar -> T0 (+xg(t+1)) -> gbar -> T1(final) -> gbar.
// Barriers are GROUP-LOCAL (32 blocks sharing bm).
// ---------------------------------------------------------------------------
__global__ __launch_bounds__(256, 1) void scan_all(
    const float* __restrict__ x,
    const float* __restrict__ Wxg,
    const float* __restrict__ rkp,
    const float* __restrict__ tkp0,
    const float* __restrict__ tkp1,
    const float* __restrict__ bias,
    const float* __restrict__ tb,
    float* hT, float* h1aT, float* h1bT, float* prl,
    float* xg0, float* xg1, float* out, unsigned* bar)
{
    __shared__ float As[64][36];      // [k][m], pad->36 keeps b128 aligned
    __shared__ float Ws[64][80];      // [k][n] (RT uses 64 cols, XG 80)
    __shared__ float RedF[10240];     // cross-wave reduction scratch (40 KB)

    const int tid = threadIdx.x;
    const int bid = blockIdx.x;
    const int bm = (bid >> 5) * 32;
    const int bn = (bid & 31) * 64;
    const int bnx = (bid & 31) * 80;
    const int lane = tid & 63;
    const int c8 = lane >> 3;
    const int ub = (bn >> 2) + c8 * 2;   // base u for this lane (2 u's)

    unsigned* cnt = bar + (bid >> 5) * 32;   // group counter, 128B apart
    unsigned phase = 0;

    const float* bias0 = bias;
    const float* bias1 = bias + G5;
    const float* tb0 = tb;
    const float* tb1 = tb + 3 * UU;

    // xg for t=0
    xg_phase(x, Wxg, bias0, xg0, 0, bm, bnx, tid, As, Ws, RedF);
    gbar(cnt, phase);

    float* xgc = xg0;
    float* xgn = xg1;

    for (int t = 0; t < TT; ++t) {
        // ---- R: hg = h @ rkp ; gates -> h1a, pre_l ----
        {
            float s[8]; int row;
            rt_gemm(hT, rkp, bm, bn, tid, As, Ws, RedF, s, row);
            const float* xr_ = xgc + (size_t)row * G5;
#pragma unroll
            for (int uu = 0; uu < 2; ++uu) {
                int u = ub + uu;
                float z  = hsig(ld_sys(xr_ + u) + s[uu * 4 + 0] + bias1[u]);
                float r  = hsig(ld_sys(xr_ + UU + u) + s[uu * 4 + 1] + bias1[UU + u]);
                float hh = tanhf(ld_sys(xr_ + 2 * UU + u) + r * (s[uu * 4 + 2] + bias1[2 * UU + u]));
                float hold = ld_sys(&hT[(size_t)u * BB + row]);
                st_sys(&h1aT[(size_t)u * BB + row], z * hold + (1.f - z) * hh);
                st_sys(&prl[(size_t)row * UU + u],
                       ld_sys(xr_ + 3 * UU + u) + s[uu * 4 + 3] + bias1[3 * UU + u]);
            }
        }
        gbar(cnt, phase);

        // ---- T0: tg = h1a @ tkp0 ; gates -> h1b ; plus xg(t+1) ----
        {
            float s[8]; int row;
            rt_gemm(h1aT, tkp0, bm, bn, tid, As, Ws, RedF, s, row);
#pragma unroll
            for (int uu = 0; uu < 2; ++uu) {
                int u = ub + uu;
                float zt = hsig(s[uu * 4 + 0] + tb0[u]);
                float rt = hsig(s[uu * 4 + 1] + tb0[UU + u]);
                float ht = tanhf(rt * (s[uu * 4 + 2] + tb0[2 * UU + u]));
                float h1v = ld_sys(&h1aT[(size_t)u * BB + row]);
                st_sys(&h1bT[(size_t)u * BB + row], zt * h1v + (1.f - zt) * ht);
            }
        }
        if (t + 1 < TT)
            xg_phase(x, Wxg, bias0, xgn, t + 1, bm, bnx, tid, As, Ws, RedF);
        gbar(cnt, phase);

        // ---- T1 (final): tg = h1b @ tkp1 ; gates + output gate -> h, out ----
        {
            float s[8]; int row;
            rt_gemm(h1bT, tkp1, bm, bn, tid, As, Ws, RedF, s, row);
#pragma unroll
            for (int uu = 0; uu < 2; ++uu) {
                int u = ub + uu;
                float zt = hsig(s[uu * 4 + 0] + tb1[u]);
                float rt = hsig(s[uu * 4 + 1] + tb1[UU + u]);
                float ht = tanhf(rt * (s[uu * 4 + 2] + tb1[2 * UU + u]));
                float h1v = ld_sys(&h1bT[(size_t)u * BB + row]);
                float h2 = zt * h1v + (1.f - zt) * ht;
                float l = hsig(ld_sys(&prl[(size_t)row * UU + u]));
                float xl2 = ld_sys(&xgc[(size_t)row * G5 + 4 * UU + u]);
                float ho = l * h2 + (1.f - l) * tanhf(xl2);
                st_sys(&hT[(size_t)u * BB + row], ho);
                out[((size_t)row * TT + t) * UU + u] = ho;   // host-read only
            }
        }
        gbar(cnt, phase);

        float* tmp = xgc; xgc = xgn; xgn = tmp;
    }
}

extern "C" void kernel_launch(void* const* d_in, const int* in_sizes, int n_in,
                              void* d_out, int out_size, void* d_ws, size_t ws_size,
                              hipStream_t stream) {
    const float* x      = (const float*)d_in[0];  // (B,T,D)
    const float* h0     = (const float*)d_in[1];  // (B,U)
    const float* kernel = (const float*)d_in[2];  // (D,5U)
    const float* rk     = (const float*)d_in[3];  // (U,4U)
    const float* tk     = (const float*)d_in[4];  // (2,U,3U)
    const float* bias   = (const float*)d_in[5];  // (2,5U)
    const float* tb     = (const float*)d_in[6];  // (2,3U)
    float* out = (float*)d_out;

    // workspace layout (floats); barrier counters occupy first 1024 B
    unsigned* bar = (unsigned*)d_ws;
    float* base = (float*)d_ws + 256;
    float* rkp  = base;                               // 512*2048
    float* tkp0 = rkp  + (size_t)UU * G4;             // 512*2048
    float* tkp1 = tkp0 + (size_t)UU * G4;             // 512*2048
    float* hT   = tkp1 + (size_t)UU * G4;             // U*B (transposed state)
    float* h1aT = hT   + (size_t)BB * UU;
    float* h1bT = h1aT + (size_t)BB * UU;
    float* prl  = h1bT + (size_t)BB * UU;
    float* xg0  = prl  + (size_t)BB * UU;             // B*5U
    float* xg1  = xg0  + (size_t)BB * G5;             // B*5U

    hipMemsetAsync(d_ws, 0, 1024, stream);   // zero barrier counters
    pack_weights<<<dim3((UU * G4) / 256), dim3(256), 0, stream>>>(rk, tk, rkp, tkp0, tkp1);
    init_hT<<<dim3((BB * UU) / 256), dim3(256), 0, stream>>>(h0, hT);

    // Plain launch (graph-capture safe). Residency guaranteed by capacity:
    // 70656 B LDS/block -> <=2 blocks/CU, 256 blocks <= 256 CUs * 2.
    scan_all<<<dim3(NBLK), dim3(256), 0, stream>>>(
        x, kernel, rkp, tkp0, tkp1, bias, tb,
        hT, h1aT, h1bT, prl, xg0, xg1, out, bar);
}